// Round 1
// baseline (250.865 us; speedup 1.0000x reference)
//
#include <hip/hip_runtime.h>
#include <hip/hip_bf16.h>

// Problem constants
// B=16, N=8, C=3, H=64, W=96; PRED_BITS=2; CONV_CH=16, FC=100, FMAP 16x24 (=384 pos, 6144 feat)
// Binary conv factorizes: conv(concat(si,sj),Wb) = conv(si,Wb[:, :3]) + conv(sj,Wb[:,3:])

typedef __attribute__((ext_vector_type(8))) short bf16x8;
typedef __attribute__((ext_vector_type(4))) float f32x4;

__device__ inline unsigned short bf16u(float x) {
    __hip_bfloat16 h = __float2bfloat16(x);
    return __builtin_bit_cast(unsigned short, h);
}

// ---------------------------------------------------------------------------
// Kernel 1: fused 48-channel conv over every image (3 states x 128 images),
// split into 2 oy-halves per image. Block = 192 threads (one per output pos).
// Writes: unary h1 (relu+bias, bf16) directly into A rows [3072..3456);
//         yf (= conv first-half + bc_b, fp32), ys (= conv second-half, fp32).
// ---------------------------------------------------------------------------
__global__ __launch_bounds__(192) void conv48_kernel(
    const float* __restrict__ s0, const float* __restrict__ s1, const float* __restrict__ s2,
    const float* __restrict__ Wcu, const float* __restrict__ bcu,
    const float* __restrict__ Wcb, const float* __restrict__ bcb,
    unsigned short* __restrict__ A, float* __restrict__ yf, float* __restrict__ ys)
{
    const int bx  = blockIdx.x;          // si*256 + img*2 + half
    const int si  = bx >> 8;
    const int rem = bx & 255;
    const int img = rem >> 1;
    const int half = rem & 1;
    const float* simg = (si == 0 ? s0 : (si == 1 ? s1 : s2)) + (long)img * (3 * 64 * 96);

    // padded LDS tile: 3 ch x 36 rows x 104 cols (left pad 4, logical ix -> col ix+4)
    __shared__ __align__(16) float lds[3 * 36 * 104];
    const int tid = threadIdx.x;

    for (int t = tid; t < (3 * 36 * 104) / 4; t += 192)
        ((float4*)lds)[t] = make_float4(0.f, 0.f, 0.f, 0.f);
    __syncthreads();

    const int y0 = half * 32 - 2;        // first input row of this tile
    for (int idx = tid; idx < 108 * 4; idx += 192) {
        int rowid = idx >> 2, q = idx & 3;
        int c = rowid / 36, rl = rowid % 36;
        int y = y0 + rl;
        if (y >= 0 && y < 64) {
            const float4* src = (const float4*)(simg + c * 6144 + y * 96) + q * 6;
            float4* dst = (float4*)(lds + (c * 36 + rl) * 104 + 4) + q * 6;
#pragma unroll
            for (int i = 0; i < 6; ++i) dst[i] = src[i];
        }
    }
    __syncthreads();

    const int oyl = tid / 24;            // 0..7
    const int ox  = tid % 24;

    float accu[16], accf[16], accs[16];
#pragma unroll
    for (int ch = 0; ch < 16; ++ch) { accu[ch] = 0.f; accf[ch] = 0.f; accs[ch] = 0.f; }

    for (int c = 0; c < 3; ++c) {
        for (int ky = 0; ky < 8; ++ky) {
            for (int kx = 0; kx < 8; ++kx) {
                float v = lds[(c * 36 + oyl * 4 + ky) * 104 + ox * 4 + kx + 2];
                int e = (c * 8 + ky) * 8 + kx;   // uniform -> weights become s_loads
#pragma unroll
                for (int ch = 0; ch < 16; ++ch) {
                    accu[ch] = fmaf(v, Wcu[ch * 192 + e],       accu[ch]);
                    accf[ch] = fmaf(v, Wcb[ch * 384 + e],       accf[ch]);
                    accs[ch] = fmaf(v, Wcb[ch * 384 + 192 + e], accs[ch]);
                }
            }
        }
    }

    const int opos = (half * 8 + oyl) * 24 + ox;
    const long im = (long)si * 128 + img;
    unsigned short* Arow = A + (3072 + im) * 6144;
    float* yfr = yf + im * 6144;
    float* ysr = ys + im * 6144;
#pragma unroll
    for (int ch = 0; ch < 16; ++ch) {
        float u = accu[ch] + bcu[ch];
        Arow[ch * 384 + opos] = bf16u(u > 0.f ? u : 0.f);
        yfr[ch * 384 + opos] = accf[ch] + bcb[ch];   // bias folded into yf
        ysr[ch * 384 + opos] = accs[ch];
    }
}

// ---------------------------------------------------------------------------
// Kernel 2: expand pair features: A[row(si,b,i,j)][k] = bf16(relu(yf[si,b,i][k]+ys[si,b,j][k]))
// Block per (si,b,i): reuses the yf row across all 8 j's.
// ---------------------------------------------------------------------------
__global__ __launch_bounds__(256) void expand_kernel(
    const float* __restrict__ yf, const float* __restrict__ ys, unsigned short* __restrict__ A)
{
    const int bx  = blockIdx.x;          // si*128 + b*8 + i
    const int si  = bx >> 7;
    const int rem = bx & 127;
    const int b   = rem >> 3;
    const int tid = threadIdx.x;
    const float* fr = yf + (long)bx * 6144;
    const long rowbase = ((long)si * 1024 + (long)b * 64 + (long)(rem & 7) * 8) * 6144;

    for (int chunk = 0; chunk < 6; ++chunk) {
        int k = chunk * 1024 + tid * 4;
        float4 vf = *(const float4*)(fr + k);
#pragma unroll
        for (int j = 0; j < 8; ++j) {
            float4 vs = *(const float4*)(ys + ((long)si * 128 + b * 8 + j) * 6144 + k);
            float x0 = vf.x + vs.x, x1 = vf.y + vs.y, x2 = vf.z + vs.z, x3 = vf.w + vs.w;
            ushort4 o;
            o.x = bf16u(x0 > 0.f ? x0 : 0.f);
            o.y = bf16u(x1 > 0.f ? x1 : 0.f);
            o.z = bf16u(x2 > 0.f ? x2 : 0.f);
            o.w = bf16u(x3 > 0.f ? x3 : 0.f);
            *(ushort4*)(A + rowbase + (long)j * 6144 + k) = o;
        }
    }
}

// ---------------------------------------------------------------------------
// Kernel 3: build transposed bf16 weight matrices Bt[f][k] = W2[k][f], f padded to 128.
// ---------------------------------------------------------------------------
__global__ __launch_bounds__(256) void convertB_kernel(
    const float* __restrict__ W2b, const float* __restrict__ W2u,
    unsigned short* __restrict__ Btb, unsigned short* __restrict__ Btu)
{
    const int bx = blockIdx.x;           // 0..95
    const int arr = bx / 48;
    const int k0 = (bx % 48) * 128;
    const float* W2 = arr ? W2u : W2b;
    unsigned short* Bt = arr ? Btu : Btb;
    __shared__ unsigned short lds[128 * 130];
    const int tid = threadIdx.x;

    for (int t = tid; t < 128 * 128; t += 256) {
        int kk = t >> 7, f = t & 127;
        float v = (f < 100) ? W2[(long)(k0 + kk) * 100 + f] : 0.f;
        lds[kk * 130 + f] = bf16u(v);
    }
    __syncthreads();
    for (int t = tid; t < 128 * 128; t += 256) {
        int f = t >> 7, kk = t & 127;
        Bt[(long)f * 6144 + k0 + kk] = lds[kk * 130 + f];
    }
}

// ---------------------------------------------------------------------------
// Kernel 4: split-K bf16 MFMA GEMM. M=3456 (27 tiles), N=128 (100 used), K=6144 (8 chunks).
// Block 256 thr (4 waves, 2x2), wave tile 64x64 (4x4 of 16x16x32 mfma). BK=64.
// ---------------------------------------------------------------------------
__global__ __launch_bounds__(256) void gemm_kernel(
    const unsigned short* __restrict__ A,
    const unsigned short* __restrict__ Btb, const unsigned short* __restrict__ Btu,
    float* __restrict__ partial)
{
    const int tid = threadIdx.x;
    const int mt = blockIdx.x % 27;
    const int kc = blockIdx.x / 27;      // 0..7
    const unsigned short* Bt = (mt < 24) ? Btb : Btu;

    __shared__ __align__(16) unsigned short lsA[128 * 72];   // +8 pad vs 64
    __shared__ __align__(16) unsigned short lsB[128 * 72];

    const int lane = tid & 63;
    const int w  = tid >> 6;
    const int wr = w & 1;
    const int wc = w >> 1;
    const int quad = lane >> 4;
    const int lcol = lane & 15;

    f32x4 acc[4][4];
#pragma unroll
    for (int i = 0; i < 4; ++i)
#pragma unroll
        for (int j = 0; j < 4; ++j) acc[i][j] = (f32x4){0.f, 0.f, 0.f, 0.f};

    const int r = tid >> 1;
    const int h = tid & 1;
    const long arow = (long)(mt * 128 + r) * 6144;
    const long brow = (long)r * 6144;
    const int kbase0 = kc * 768;

    for (int it = 0; it < 12; ++it) {
        const int kb = kbase0 + it * 64;
        const unsigned short* ga = A + arow + kb + h * 32;
        const unsigned short* gb = Bt + brow + kb + h * 32;
        unsigned short* da = lsA + r * 72 + h * 32;
        unsigned short* db = lsB + r * 72 + h * 32;
#pragma unroll
        for (int i = 0; i < 4; ++i) {
            *(uint4*)(da + i * 8) = *(const uint4*)(ga + i * 8);
            *(uint4*)(db + i * 8) = *(const uint4*)(gb + i * 8);
        }
        __syncthreads();
#pragma unroll
        for (int ks = 0; ks < 2; ++ks) {
            bf16x8 af[4], bfr[4];
#pragma unroll
            for (int t = 0; t < 4; ++t)
                af[t] = *(const bf16x8*)(lsA + (wr * 64 + t * 16 + lcol) * 72 + ks * 32 + quad * 8);
#pragma unroll
            for (int t = 0; t < 4; ++t)
                bfr[t] = *(const bf16x8*)(lsB + (wc * 64 + t * 16 + lcol) * 72 + ks * 32 + quad * 8);
#pragma unroll
            for (int i = 0; i < 4; ++i)
#pragma unroll
                for (int j = 0; j < 4; ++j)
                    acc[i][j] = __builtin_amdgcn_mfma_f32_16x16x32_bf16(af[i], bfr[j], acc[i][j], 0, 0, 0);
        }
        __syncthreads();
    }

    float* out = partial + (long)(kc * 27 + mt) * 16384;
#pragma unroll
    for (int i = 0; i < 4; ++i)
#pragma unroll
        for (int j = 0; j < 4; ++j)
#pragma unroll
            for (int reg = 0; reg < 4; ++reg) {
                int rr = wr * 64 + i * 16 + quad * 4 + reg;   // C/D: row = quad*4+reg
                int cc = wc * 64 + j * 16 + lcol;             //      col = lane&15
                out[rr * 128 + cc] = acc[i][j][reg];
            }
}

// ---------------------------------------------------------------------------
// Kernel 5: split-K reduce + bias + relu -> h2 (3456 x 112, fp32; f>=100 zeroed)
// ---------------------------------------------------------------------------
__global__ __launch_bounds__(256) void reduce_kernel(
    const float* __restrict__ partial,
    const float* __restrict__ b2b, const float* __restrict__ b2u,
    float* __restrict__ h2)
{
    int gid = blockIdx.x * 256 + threadIdx.x;
    if (gid >= 3456 * 112) return;
    int m = gid / 112, f = gid % 112;
    int mt = m >> 7, rr = m & 127;
    float s = 0.f;
#pragma unroll
    for (int kc = 0; kc < 8; ++kc)
        s += partial[((long)(kc * 27 + mt) * 128 + rr) * 128 + f];
    float v = 0.f;
    if (f < 100) {
        s += (m < 3072) ? b2b[f] : b2u[f];
        v = s > 0.f ? s : 0.f;
    }
    h2[(long)m * 112 + f] = v;
}

// ---------------------------------------------------------------------------
// Kernel 6: FC2 + gumbel softmax (2-way -> sigmoid) + compaction/mask -> d_out
// One thread per OUTPUT position (gather form of take_along_axis).
// ---------------------------------------------------------------------------
__global__ __launch_bounds__(256) void head_kernel(
    const float* __restrict__ h2,
    const float* __restrict__ W3b, const float* __restrict__ b3b,
    const float* __restrict__ W3u, const float* __restrict__ b3u,
    const float* __restrict__ gb, const float* __restrict__ gu,
    const int* __restrict__ nobj, const float* __restrict__ temp_p,
    float* __restrict__ out)
{
    int gid = blockIdx.x * 256 + threadIdx.x;
    if (gid >= 3456) return;
    float temp = temp_p[0];
    if (gid < 3072) {
        int si = gid / 1024, rem = gid % 1024;
        int b = rem >> 6, p = rem & 63;
        int n = nobj[b];
        int ns = n > 0 ? n : 1;
        int k = (p / ns) * 8 + (p % ns);
        int valid = p < n * n;
        int kk = k < 63 ? k : 63;
        const float* hr = h2 + (long)(si * 1024 + b * 64 + kk) * 112;
        float l0 = b3b[0], l1 = b3b[1];
        for (int f = 0; f < 100; ++f) {
            float hv = hr[f];
            l0 = fmaf(hv, W3b[f * 2],     l0);
            l1 = fmaf(hv, W3b[f * 2 + 1], l1);
        }
        const float* g = gb + (long)(si * 1024 + b * 64 + kk) * 2;
        float d = ((l0 + g[0]) - (l1 + g[1])) / temp;
        float p0 = 1.f / (1.f + expf(-d));
        float* o = out + (long)si * 2048 + (b * 64 + p) * 2;
        o[0] = valid ? p0 : 0.f;
        o[1] = valid ? 1.f - p0 : 0.f;
    } else {
        int r = gid - 3072;
        int si = r / 128, q = r % 128;
        int b = q >> 3, i = q & 7;
        const float* hr = h2 + (long)(3072 + r) * 112;
        float l0 = b3u[0], l1 = b3u[1];
        for (int f = 0; f < 100; ++f) {
            float hv = hr[f];
            l0 = fmaf(hv, W3u[f * 2],     l0);
            l1 = fmaf(hv, W3u[f * 2 + 1], l1);
        }
        const float* g = gu + (long)si * 256 + (b * 8 + i) * 2;
        float d = ((l0 + g[0]) - (l1 + g[1])) / temp;
        float p0 = 1.f / (1.f + expf(-d));
        int valid = i < nobj[b];
        float* o = out + 6144 + (long)si * 256 + (b * 8 + i) * 2;
        o[0] = valid ? p0 : 0.f;
        o[1] = valid ? 1.f - p0 : 0.f;
    }
}

// ---------------------------------------------------------------------------
// Workspace layout (bytes)
// ---------------------------------------------------------------------------
static const size_t A_OFF    = 0;                          // 3456*6144 bf16 = 42,467,328
static const size_t YF_OFF   = 42467328;                   // 384*6144 f32  =  9,437,184
static const size_t YS_OFF   = 51904512;                   // 384*6144 f32  =  9,437,184
static const size_t BTB_OFF  = 61341696;                   // 128*6144 bf16 =  1,572,864
static const size_t BTU_OFF  = 62914560;                   // 128*6144 bf16 =  1,572,864
static const size_t PART_OFF = 64487424;                   // 8*27*128*128 f32 = 14,155,776
static const size_t H2_OFF   = 78643200;                   // 3456*112 f32  =  1,548,288
// total = 80,191,488 bytes

extern "C" void kernel_launch(void* const* d_in, const int* in_sizes, int n_in,
                              void* d_out, int out_size, void* d_ws, size_t ws_size,
                              hipStream_t stream) {
    const float* state   = (const float*)d_in[0];
    const float* state_n = (const float*)d_in[1];
    const float* state_t = (const float*)d_in[2];
    const int*   n_obj   = (const int*)  d_in[3];
    const float* temp    = (const float*)d_in[4];
    const float* g_un    = (const float*)d_in[5];
    const float* g_bin   = (const float*)d_in[6];
    const float* Wc_u    = (const float*)d_in[7];
    const float* bc_u    = (const float*)d_in[8];
    const float* W2_u    = (const float*)d_in[9];
    const float* b2_u    = (const float*)d_in[10];
    const float* W3_u    = (const float*)d_in[11];
    const float* b3_u    = (const float*)d_in[12];
    const float* Wc_b    = (const float*)d_in[13];
    const float* bc_b    = (const float*)d_in[14];
    const float* W2_b    = (const float*)d_in[15];
    const float* b2_b    = (const float*)d_in[16];
    const float* W3_b    = (const float*)d_in[17];
    const float* b3_b    = (const float*)d_in[18];

    char* ws = (char*)d_ws;
    unsigned short* A   = (unsigned short*)(ws + A_OFF);
    float*          yf  = (float*)(ws + YF_OFF);
    float*          ys  = (float*)(ws + YS_OFF);
    unsigned short* Btb = (unsigned short*)(ws + BTB_OFF);
    unsigned short* Btu = (unsigned short*)(ws + BTU_OFF);
    float*          prt = (float*)(ws + PART_OFF);
    float*          h2  = (float*)(ws + H2_OFF);
    float*          out = (float*)d_out;

    hipLaunchKernelGGL(conv48_kernel, dim3(768), dim3(192), 0, stream,
                       state, state_n, state_t, Wc_u, bc_u, Wc_b, bc_b, A, yf, ys);
    hipLaunchKernelGGL(convertB_kernel, dim3(96), dim3(256), 0, stream,
                       W2_b, W2_u, Btb, Btu);
    hipLaunchKernelGGL(expand_kernel, dim3(384), dim3(256), 0, stream,
                       yf, ys, A);
    hipLaunchKernelGGL(gemm_kernel, dim3(216), dim3(256), 0, stream,
                       A, Btb, Btu, prt);
    hipLaunchKernelGGL(reduce_kernel, dim3(1512), dim3(256), 0, stream,
                       prt, b2_b, b2_u, h2);
    hipLaunchKernelGGL(head_kernel, dim3(14), dim3(256), 0, stream,
                       h2, W3_b, b3_b, W3_u, b3_u, g_bin, g_un, n_obj, temp, out);
}

// Round 2
// 182.033 us; speedup vs baseline: 1.3781x; 1.3781x over previous
//
#include <hip/hip_runtime.h>
#include <hip/hip_bf16.h>

// Problem constants
// B=16, N=8, C=3, H=64, W=96; PRED_BITS=2; CONV_CH=16, FC=100, FMAP 16x24 (=384 pos, 6144 feat)
// Binary conv factorizes: conv(concat(si,sj),Wb) = conv(si,Wb[:, :3]) + conv(sj,Wb[:,3:])
// Conv as implicit-im2col MFMA GEMM: M=positions, N=48 out-ch, K=192 taps.

typedef __attribute__((ext_vector_type(8))) short bf16x8;
typedef __attribute__((ext_vector_type(4))) float f32x4;

__device__ inline unsigned short bf16u(float x) {
    __hip_bfloat16 h = __float2bfloat16(x);
    return __builtin_bit_cast(unsigned short, h);
}

// ---------------------------------------------------------------------------
// Kernel 1: convertB + conv-weight-fragment builder.
// Blocks 0..95: Bt[f][k] = W2[k][f] transpose (bf16, f padded to 128).
// Block 96: BwFrag[(t6*3+nt)*64+lane][j] = B-fragment of conv weights,
//   nt=0 unary Wcu, nt=1 binary first-half, nt=2 binary second-half;
//   k = t6*32 + (lane>>4)*8 + j (tap e), n = lane&15 (out channel).
// ---------------------------------------------------------------------------
__global__ __launch_bounds__(256) void convertB_kernel(
    const float* __restrict__ W2b, const float* __restrict__ W2u,
    const float* __restrict__ Wcu, const float* __restrict__ Wcb,
    unsigned short* __restrict__ Btb, unsigned short* __restrict__ Btu,
    unsigned short* __restrict__ BwFrag)
{
    const int bx = blockIdx.x;
    const int tid = threadIdx.x;
    if (bx == 96) {
        for (int t = tid; t < 18 * 64; t += 256) {
            int lane = t & 63, g = t >> 6;      // g = t6*3 + nt
            int t6 = g / 3, nt = g % 3;
            int ch = lane & 15, kq = lane >> 4;
            unsigned short* dst = BwFrag + (long)t * 8;
#pragma unroll
            for (int j = 0; j < 8; ++j) {
                int e = t6 * 32 + kq * 8 + j;   // tap index (c*8+ky)*8+kx
                float v = (nt == 0) ? Wcu[ch * 192 + e]
                        : (nt == 1) ? Wcb[ch * 384 + e]
                                    : Wcb[ch * 384 + 192 + e];
                dst[j] = bf16u(v);
            }
        }
        return;
    }
    const int arr = bx / 48;
    const int k0 = (bx % 48) * 128;
    const float* W2 = arr ? W2u : W2b;
    unsigned short* Bt = arr ? Btu : Btb;
    __shared__ unsigned short lds[128 * 130];
    for (int t = tid; t < 128 * 128; t += 256) {
        int kk = t >> 7, f = t & 127;
        float v = (f < 100) ? W2[(long)(k0 + kk) * 100 + f] : 0.f;
        lds[kk * 130 + f] = bf16u(v);
    }
    __syncthreads();
    for (int t = tid; t < 128 * 128; t += 256) {
        int f = t >> 7, kk = t & 127;
        Bt[(long)f * 6144 + k0 + kk] = lds[kk * 130 + f];
    }
}

// ---------------------------------------------------------------------------
// Kernel 2: MFMA implicit-im2col conv. Block = half an image (192 out pos),
// 256 threads = 4 waves, each wave 3 m-tiles of 16 positions.
// LDS image tile: 3 ch x 36 rows x 106 cols bf16 (stride 53 dwords = odd bank
// shift per row -> A-frag ds_reads are <=2-way = conflict-free).
// Writes: unary h1 (relu, bf16) to A rows [3072..3456); yf (+bias), ys (f32).
// ---------------------------------------------------------------------------
#define CL_STRIDE 106
#define CL_CH (36 * CL_STRIDE)   // 3816
__global__ __launch_bounds__(256) void convmfma_kernel(
    const float* __restrict__ s0, const float* __restrict__ s1, const float* __restrict__ s2,
    const unsigned short* __restrict__ BwFrag,
    const float* __restrict__ bcu, const float* __restrict__ bcb,
    unsigned short* __restrict__ A, float* __restrict__ yf, float* __restrict__ ys)
{
    const int bx  = blockIdx.x;          // si*256 + img*2 + half
    const int si  = bx >> 8;
    const int rem = bx & 255;
    const int img = rem >> 1;
    const int h   = rem & 1;
    const float* simg = (si == 0 ? s0 : (si == 1 ? s1 : s2)) + (long)img * 18432;

    __shared__ __align__(16) unsigned short ldsimg[3 * CL_CH];   // 22,896 B
    const int tid  = threadIdx.x;
    const int lane = tid & 63;
    const int w    = tid >> 6;
    const int quad = lane >> 4;
    const int lcol = lane & 15;

    // weight B-fragments (coalesced 16B loads, 72 VGPRs)
    bf16x8 bw[6][3];
#pragma unroll
    for (int t6 = 0; t6 < 6; ++t6)
#pragma unroll
        for (int nt = 0; nt < 3; ++nt)
            bw[t6][nt] = *(const bf16x8*)(BwFrag + ((t6 * 3 + nt) * 64 + lane) * 8);

    // zero-fill (borders must be 0)
    for (int t = tid; t < (3 * CL_CH) / 2; t += 256)
        ((unsigned*)ldsimg)[t] = 0u;
    __syncthreads();

    // stage: LDS row r <-> input row iy = h*32 + r - 2; col ix -> element ix+4
    const int y0 = h * 32;
    for (int t = tid; t < 3 * 36 * 24; t += 256) {
        int c = t / 864, rq = t % 864, r = rq / 24, q = rq % 24;
        int iy = y0 + r - 2;
        if (iy >= 0 && iy < 64) {
            float4 v = *((const float4*)(simg + c * 6144 + iy * 96) + q);
            unsigned lo = (unsigned)bf16u(v.x) | ((unsigned)bf16u(v.y) << 16);
            unsigned hi = (unsigned)bf16u(v.z) | ((unsigned)bf16u(v.w) << 16);
            unsigned* dst = (unsigned*)(ldsimg + c * CL_CH + r * CL_STRIDE + q * 4 + 4);
            dst[0] = lo; dst[1] = hi;
        }
    }
    __syncthreads();

    const float bu = bcu[lcol];
    const float bb = bcb[lcol];
    const long im = (long)si * 128 + img;
    unsigned short* Arow = A + (3072 + im) * 6144;
    float* yfr = yf + im * 6144;
    float* ysr = ys + im * 6144;

#pragma unroll
    for (int mi = 0; mi < 3; ++mi) {
        const int mt = w * 3 + mi;           // m-tile 0..11
        const int p  = mt * 16 + lcol;       // this lane's A-row (position)
        const int oyl = p / 24, ox = p % 24;
        f32x4 a0 = {0.f, 0.f, 0.f, 0.f}, a1 = a0, a2 = a0;
#pragma unroll
        for (int t6 = 0; t6 < 6; ++t6) {
            int g  = t6 * 4 + quad;          // tap group: c = g/8, ky = g%8
            int c  = g >> 3, ky = g & 7;
            const unsigned* lp = (const unsigned*)(ldsimg + c * CL_CH + (oyl * 4 + ky) * CL_STRIDE + ox * 4 + 2);
            bf16x8 afr;
            unsigned* ap = (unsigned*)&afr;
            ap[0] = lp[0]; ap[1] = lp[1]; ap[2] = lp[2]; ap[3] = lp[3];
            a0 = __builtin_amdgcn_mfma_f32_16x16x32_bf16(afr, bw[t6][0], a0, 0, 0, 0);
            a1 = __builtin_amdgcn_mfma_f32_16x16x32_bf16(afr, bw[t6][1], a1, 0, 0, 0);
            a2 = __builtin_amdgcn_mfma_f32_16x16x32_bf16(afr, bw[t6][2], a2, 0, 0, 0);
        }
        // C/D layout: out position = mt*16 + quad*4 + reg, out ch = lcol
#pragma unroll
        for (int reg = 0; reg < 4; ++reg) {
            int pr = h * 192 + mt * 16 + quad * 4 + reg;
            float u = a0[reg] + bu;
            Arow[lcol * 384 + pr] = bf16u(u > 0.f ? u : 0.f);
            yfr[lcol * 384 + pr] = a1[reg] + bb;    // binary bias folded into yf
            ysr[lcol * 384 + pr] = a2[reg];
        }
    }
}

// ---------------------------------------------------------------------------
// Kernel 3: expand pair features: A[row(si,b,i,j)][k] = bf16(relu(yf[si,b,i][k]+ys[si,b,j][k]))
// ---------------------------------------------------------------------------
__global__ __launch_bounds__(256) void expand_kernel(
    const float* __restrict__ yf, const float* __restrict__ ys, unsigned short* __restrict__ A)
{
    const int bx  = blockIdx.x;          // si*128 + b*8 + i
    const int si  = bx >> 7;
    const int rem = bx & 127;
    const int b   = rem >> 3;
    const int tid = threadIdx.x;
    const float* fr = yf + (long)bx * 6144;
    const long rowbase = ((long)si * 1024 + (long)b * 64 + (long)(rem & 7) * 8) * 6144;

    for (int chunk = 0; chunk < 6; ++chunk) {
        int k = chunk * 1024 + tid * 4;
        float4 vf = *(const float4*)(fr + k);
#pragma unroll
        for (int j = 0; j < 8; ++j) {
            float4 vs = *(const float4*)(ys + ((long)si * 128 + b * 8 + j) * 6144 + k);
            float x0 = vf.x + vs.x, x1 = vf.y + vs.y, x2 = vf.z + vs.z, x3 = vf.w + vs.w;
            ushort4 o;
            o.x = bf16u(x0 > 0.f ? x0 : 0.f);
            o.y = bf16u(x1 > 0.f ? x1 : 0.f);
            o.z = bf16u(x2 > 0.f ? x2 : 0.f);
            o.w = bf16u(x3 > 0.f ? x3 : 0.f);
            *(ushort4*)(A + rowbase + (long)j * 6144 + k) = o;
        }
    }
}

// ---------------------------------------------------------------------------
// Kernel 4: split-K bf16 MFMA GEMM. M=3456 (27 tiles), N=128 (100 used), K=6144 (8 chunks).
// ---------------------------------------------------------------------------
__global__ __launch_bounds__(256) void gemm_kernel(
    const unsigned short* __restrict__ A,
    const unsigned short* __restrict__ Btb, const unsigned short* __restrict__ Btu,
    float* __restrict__ partial)
{
    const int tid = threadIdx.x;
    const int mt = blockIdx.x % 27;
    const int kc = blockIdx.x / 27;      // 0..7
    const unsigned short* Bt = (mt < 24) ? Btb : Btu;

    __shared__ __align__(16) unsigned short lsA[128 * 72];
    __shared__ __align__(16) unsigned short lsB[128 * 72];

    const int lane = tid & 63;
    const int w  = tid >> 6;
    const int wr = w & 1;
    const int wc = w >> 1;
    const int quad = lane >> 4;
    const int lcol = lane & 15;

    f32x4 acc[4][4];
#pragma unroll
    for (int i = 0; i < 4; ++i)
#pragma unroll
        for (int j = 0; j < 4; ++j) acc[i][j] = (f32x4){0.f, 0.f, 0.f, 0.f};

    const int r = tid >> 1;
    const int h = tid & 1;
    const long arow = (long)(mt * 128 + r) * 6144;
    const long brow = (long)r * 6144;
    const int kbase0 = kc * 768;

    for (int it = 0; it < 12; ++it) {
        const int kb = kbase0 + it * 64;
        const unsigned short* ga = A + arow + kb + h * 32;
        const unsigned short* gb = Bt + brow + kb + h * 32;
        unsigned short* da = lsA + r * 72 + h * 32;
        unsigned short* db = lsB + r * 72 + h * 32;
#pragma unroll
        for (int i = 0; i < 4; ++i) {
            *(uint4*)(da + i * 8) = *(const uint4*)(ga + i * 8);
            *(uint4*)(db + i * 8) = *(const uint4*)(gb + i * 8);
        }
        __syncthreads();
#pragma unroll
        for (int ks = 0; ks < 2; ++ks) {
            bf16x8 af[4], bfr[4];
#pragma unroll
            for (int t = 0; t < 4; ++t)
                af[t] = *(const bf16x8*)(lsA + (wr * 64 + t * 16 + lcol) * 72 + ks * 32 + quad * 8);
#pragma unroll
            for (int t = 0; t < 4; ++t)
                bfr[t] = *(const bf16x8*)(lsB + (wc * 64 + t * 16 + lcol) * 72 + ks * 32 + quad * 8);
#pragma unroll
            for (int i = 0; i < 4; ++i)
#pragma unroll
                for (int j = 0; j < 4; ++j)
                    acc[i][j] = __builtin_amdgcn_mfma_f32_16x16x32_bf16(af[i], bfr[j], acc[i][j], 0, 0, 0);
        }
        __syncthreads();
    }

    float* out = partial + (long)(kc * 27 + mt) * 16384;
#pragma unroll
    for (int i = 0; i < 4; ++i)
#pragma unroll
        for (int j = 0; j < 4; ++j)
#pragma unroll
            for (int reg = 0; reg < 4; ++reg) {
                int rr = wr * 64 + i * 16 + quad * 4 + reg;
                int cc = wc * 64 + j * 16 + lcol;
                out[rr * 128 + cc] = acc[i][j][reg];
            }
}

// ---------------------------------------------------------------------------
// Kernel 5: split-K reduce + bias + relu -> h2 (3456 x 112, fp32; f>=100 zeroed)
// ---------------------------------------------------------------------------
__global__ __launch_bounds__(256) void reduce_kernel(
    const float* __restrict__ partial,
    const float* __restrict__ b2b, const float* __restrict__ b2u,
    float* __restrict__ h2)
{
    int gid = blockIdx.x * 256 + threadIdx.x;
    if (gid >= 3456 * 112) return;
    int m = gid / 112, f = gid % 112;
    int mt = m >> 7, rr = m & 127;
    float s = 0.f;
#pragma unroll
    for (int kc = 0; kc < 8; ++kc)
        s += partial[((long)(kc * 27 + mt) * 128 + rr) * 128 + f];
    float v = 0.f;
    if (f < 100) {
        s += (m < 3072) ? b2b[f] : b2u[f];
        v = s > 0.f ? s : 0.f;
    }
    h2[(long)m * 112 + f] = v;
}

// ---------------------------------------------------------------------------
// Kernel 6: FC2 + gumbel softmax (2-way -> sigmoid) + compaction/mask -> d_out
// ---------------------------------------------------------------------------
__device__ inline void fc2_dot(const float* __restrict__ hr, const float* __restrict__ W3,
                               float& l0, float& l1)
{
#pragma unroll 5
    for (int f4 = 0; f4 < 25; ++f4) {
        float4 hv = *(const float4*)(hr + f4 * 4);
        float4 w0 = *(const float4*)(W3 + f4 * 8);
        float4 w1 = *(const float4*)(W3 + f4 * 8 + 4);
        l0 = fmaf(hv.x, w0.x, fmaf(hv.y, w0.z, fmaf(hv.z, w1.x, fmaf(hv.w, w1.z, l0))));
        l1 = fmaf(hv.x, w0.y, fmaf(hv.y, w0.w, fmaf(hv.z, w1.y, fmaf(hv.w, w1.w, l1))));
    }
}

__global__ __launch_bounds__(64) void head_kernel(
    const float* __restrict__ h2,
    const float* __restrict__ W3b, const float* __restrict__ b3b,
    const float* __restrict__ W3u, const float* __restrict__ b3u,
    const float* __restrict__ gb, const float* __restrict__ gu,
    const int* __restrict__ nobj, const float* __restrict__ temp_p,
    float* __restrict__ out)
{
    int gid = blockIdx.x * 64 + threadIdx.x;
    if (gid >= 3456) return;
    float temp = temp_p[0];
    if (gid < 3072) {
        int si = gid / 1024, rem = gid % 1024;
        int b = rem >> 6, p = rem & 63;
        int n = nobj[b];
        int ns = n > 0 ? n : 1;
        int k = (p / ns) * 8 + (p % ns);
        int valid = p < n * n;
        int kk = k < 63 ? k : 63;
        const float* hr = h2 + (long)(si * 1024 + b * 64 + kk) * 112;
        float l0 = b3b[0], l1 = b3b[1];
        fc2_dot(hr, W3b, l0, l1);
        const float* g = gb + (long)(si * 1024 + b * 64 + kk) * 2;
        float d = ((l0 + g[0]) - (l1 + g[1])) / temp;
        float p0 = 1.f / (1.f + expf(-d));
        float* o = out + (long)si * 2048 + (b * 64 + p) * 2;
        o[0] = valid ? p0 : 0.f;
        o[1] = valid ? 1.f - p0 : 0.f;
    } else {
        int r = gid - 3072;
        int si = r / 128, q = r % 128;
        int b = q >> 3, i = q & 7;
        const float* hr = h2 + (long)(3072 + r) * 112;
        float l0 = b3u[0], l1 = b3u[1];
        fc2_dot(hr, W3u, l0, l1);
        const float* g = gu + (long)si * 256 + (b * 8 + i) * 2;
        float d = ((l0 + g[0]) - (l1 + g[1])) / temp;
        float p0 = 1.f / (1.f + expf(-d));
        int valid = i < nobj[b];
        float* o = out + 6144 + (long)si * 256 + (b * 8 + i) * 2;
        o[0] = valid ? p0 : 0.f;
        o[1] = valid ? 1.f - p0 : 0.f;
    }
}

// ---------------------------------------------------------------------------
// Workspace layout (bytes)
// ---------------------------------------------------------------------------
static const size_t A_OFF    = 0;                          // 3456*6144 bf16 = 42,467,328
static const size_t YF_OFF   = 42467328;                   // 384*6144 f32  =  9,437,184
static const size_t YS_OFF   = 51904512;                   // 384*6144 f32  =  9,437,184
static const size_t BTB_OFF  = 61341696;                   // 128*6144 bf16 =  1,572,864
static const size_t BTU_OFF  = 62914560;                   // 128*6144 bf16 =  1,572,864
static const size_t PART_OFF = 64487424;                   // 8*27*128*128 f32 = 14,155,776
static const size_t H2_OFF   = 78643200;                   // 3456*112 f32  =  1,548,288
static const size_t BWF_OFF  = 80191488;                   // 18*64*8 bf16  =     18,432
// total = 80,209,920 bytes

extern "C" void kernel_launch(void* const* d_in, const int* in_sizes, int n_in,
                              void* d_out, int out_size, void* d_ws, size_t ws_size,
                              hipStream_t stream) {
    const float* state   = (const float*)d_in[0];
    const float* state_n = (const float*)d_in[1];
    const float* state_t = (const float*)d_in[2];
    const int*   n_obj   = (const int*)  d_in[3];
    const float* temp    = (const float*)d_in[4];
    const float* g_un    = (const float*)d_in[5];
    const float* g_bin   = (const float*)d_in[6];
    const float* Wc_u    = (const float*)d_in[7];
    const float* bc_u    = (const float*)d_in[8];
    const float* W2_u    = (const float*)d_in[9];
    const float* b2_u    = (const float*)d_in[10];
    const float* W3_u    = (const float*)d_in[11];
    const float* b3_u    = (const float*)d_in[12];
    const float* Wc_b    = (const float*)d_in[13];
    const float* bc_b    = (const float*)d_in[14];
    const float* W2_b    = (const float*)d_in[15];
    const float* b2_b    = (const float*)d_in[16];
    const float* W3_b    = (const float*)d_in[17];
    const float* b3_b    = (const float*)d_in[18];

    char* ws = (char*)d_ws;
    unsigned short* A    = (unsigned short*)(ws + A_OFF);
    float*          yf   = (float*)(ws + YF_OFF);
    float*          ys   = (float*)(ws + YS_OFF);
    unsigned short* Btb  = (unsigned short*)(ws + BTB_OFF);
    unsigned short* Btu  = (unsigned short*)(ws + BTU_OFF);
    float*          prt  = (float*)(ws + PART_OFF);
    float*          h2   = (float*)(ws + H2_OFF);
    unsigned short* BwF  = (unsigned short*)(ws + BWF_OFF);
    float*          out  = (float*)d_out;

    hipLaunchKernelGGL(convertB_kernel, dim3(97), dim3(256), 0, stream,
                       W2_b, W2_u, Wc_u, Wc_b, Btb, Btu, BwF);
    hipLaunchKernelGGL(convmfma_kernel, dim3(768), dim3(256), 0, stream,
                       state, state_n, state_t, BwF, bc_u, bc_b, A, yf, ys);
    hipLaunchKernelGGL(expand_kernel, dim3(384), dim3(256), 0, stream,
                       yf, ys, A);
    hipLaunchKernelGGL(gemm_kernel, dim3(216), dim3(256), 0, stream,
                       A, Btb, Btu, prt);
    hipLaunchKernelGGL(reduce_kernel, dim3(1512), dim3(256), 0, stream,
                       prt, b2_b, b2_u, h2);
    hipLaunchKernelGGL(head_kernel, dim3(54), dim3(64), 0, stream,
                       h2, W3_b, b3_b, W3_u, b3_u, g_bin, g_un, n_obj, temp, out);
}

// Round 3
// 165.824 us; speedup vs baseline: 1.5128x; 1.0977x over previous
//
#include <hip/hip_runtime.h>
#include <hip/hip_bf16.h>

// Problem constants
// B=16, N=8, C=3, H=64, W=96; PRED_BITS=2; CONV_CH=16, FC=100, FMAP 16x24 (=384 pos, 6144 feat)
// Binary conv factorizes: conv(concat(si,sj),Wb) = conv(si,Wb[:, :3]) + conv(sj,Wb[:,3:])
// Conv as implicit-im2col MFMA GEMM: M=positions, N=48 out-ch, K=192 taps.
// Pair expansion relu(yf_i + ys_j) fused into FC1 GEMM staging (A never materialized).

typedef __attribute__((ext_vector_type(8))) short bf16x8;
typedef __attribute__((ext_vector_type(4))) float f32x4;

__device__ inline unsigned short bf16u(float x) {
    __hip_bfloat16 h = __float2bfloat16(x);
    return __builtin_bit_cast(unsigned short, h);
}

// combine two packed-bf16 pairs: relu(f + s) per element, repack to bf16x2
__device__ inline unsigned pair_relu(unsigned f, unsigned s) {
    float lo = __builtin_bit_cast(float, f << 16) + __builtin_bit_cast(float, s << 16);
    float hi = __builtin_bit_cast(float, f & 0xffff0000u) + __builtin_bit_cast(float, s & 0xffff0000u);
    lo = lo > 0.f ? lo : 0.f;
    hi = hi > 0.f ? hi : 0.f;
    return (unsigned)bf16u(lo) | ((unsigned)bf16u(hi) << 16);
}

// ---------------------------------------------------------------------------
// Kernel 1: convertB + conv-weight-fragment builder.
// Blocks 0..95: Bt[f][k] = W2[k][f] transpose (bf16, f padded to 128).
// Block 96: BwFrag = conv-weight B-fragments (unary, binary-first, binary-second).
// ---------------------------------------------------------------------------
__global__ __launch_bounds__(256) void convertB_kernel(
    const float* __restrict__ W2b, const float* __restrict__ W2u,
    const float* __restrict__ Wcu, const float* __restrict__ Wcb,
    unsigned short* __restrict__ Btb, unsigned short* __restrict__ Btu,
    unsigned short* __restrict__ BwFrag)
{
    const int bx = blockIdx.x;
    const int tid = threadIdx.x;
    if (bx == 96) {
        for (int t = tid; t < 18 * 64; t += 256) {
            int lane = t & 63, g = t >> 6;      // g = t6*3 + nt
            int t6 = g / 3, nt = g % 3;
            int ch = lane & 15, kq = lane >> 4;
            unsigned short* dst = BwFrag + (long)t * 8;
#pragma unroll
            for (int j = 0; j < 8; ++j) {
                int e = t6 * 32 + kq * 8 + j;   // tap index (c*8+ky)*8+kx
                float v = (nt == 0) ? Wcu[ch * 192 + e]
                        : (nt == 1) ? Wcb[ch * 384 + e]
                                    : Wcb[ch * 384 + 192 + e];
                dst[j] = bf16u(v);
            }
        }
        return;
    }
    const int arr = bx / 48;
    const int k0 = (bx % 48) * 128;
    const float* W2 = arr ? W2u : W2b;
    unsigned short* Bt = arr ? Btu : Btb;
    __shared__ unsigned short lds[128 * 130];
    for (int t = tid; t < 128 * 128; t += 256) {
        int kk = t >> 7, f = t & 127;
        float v = (f < 100) ? W2[(long)(k0 + kk) * 100 + f] : 0.f;
        lds[kk * 130 + f] = bf16u(v);
    }
    __syncthreads();
    for (int t = tid; t < 128 * 128; t += 256) {
        int f = t >> 7, kk = t & 127;
        Bt[(long)f * 6144 + k0 + kk] = lds[kk * 130 + f];
    }
}

// ---------------------------------------------------------------------------
// Kernel 2: MFMA implicit-im2col conv. Block = half an image (192 out pos).
// Outputs (all bf16): Au = unary h1 (relu'd), yfb = binary first-half conv
// (+bias), ysb = binary second-half conv.
// ---------------------------------------------------------------------------
#define CL_STRIDE 106
#define CL_CH (36 * CL_STRIDE)   // 3816
__global__ __launch_bounds__(256) void convmfma_kernel(
    const float* __restrict__ s0, const float* __restrict__ s1, const float* __restrict__ s2,
    const unsigned short* __restrict__ BwFrag,
    const float* __restrict__ bcu, const float* __restrict__ bcb,
    unsigned short* __restrict__ Au, unsigned short* __restrict__ yfb,
    unsigned short* __restrict__ ysb)
{
    const int bx  = blockIdx.x;          // si*256 + img*2 + half
    const int si  = bx >> 8;
    const int rem = bx & 255;
    const int img = rem >> 1;
    const int h   = rem & 1;
    const float* simg = (si == 0 ? s0 : (si == 1 ? s1 : s2)) + (long)img * 18432;

    __shared__ __align__(16) unsigned short ldsimg[3 * CL_CH];   // 22,896 B
    const int tid  = threadIdx.x;
    const int lane = tid & 63;
    const int w    = tid >> 6;
    const int quad = lane >> 4;
    const int lcol = lane & 15;

    bf16x8 bw[6][3];
#pragma unroll
    for (int t6 = 0; t6 < 6; ++t6)
#pragma unroll
        for (int nt = 0; nt < 3; ++nt)
            bw[t6][nt] = *(const bf16x8*)(BwFrag + ((t6 * 3 + nt) * 64 + lane) * 8);

    for (int t = tid; t < (3 * CL_CH) / 2; t += 256)
        ((unsigned*)ldsimg)[t] = 0u;
    __syncthreads();

    const int y0 = h * 32;
    for (int t = tid; t < 3 * 36 * 24; t += 256) {
        int c = t / 864, rq = t % 864, r = rq / 24, q = rq % 24;
        int iy = y0 + r - 2;
        if (iy >= 0 && iy < 64) {
            float4 v = *((const float4*)(simg + c * 6144 + iy * 96) + q);
            unsigned lo = (unsigned)bf16u(v.x) | ((unsigned)bf16u(v.y) << 16);
            unsigned hi = (unsigned)bf16u(v.z) | ((unsigned)bf16u(v.w) << 16);
            unsigned* dst = (unsigned*)(ldsimg + c * CL_CH + r * CL_STRIDE + q * 4 + 4);
            dst[0] = lo; dst[1] = hi;
        }
    }
    __syncthreads();

    const float bu = bcu[lcol];
    const float bb = bcb[lcol];
    const long im = (long)si * 128 + img;
    unsigned short* Aur = Au + im * 6144;
    unsigned short* yfr = yfb + im * 6144;
    unsigned short* ysr = ysb + im * 6144;

#pragma unroll
    for (int mi = 0; mi < 3; ++mi) {
        const int mt = w * 3 + mi;           // m-tile 0..11
        const int p  = mt * 16 + lcol;       // this lane's A-row (position)
        const int oyl = p / 24, ox = p % 24;
        f32x4 a0 = {0.f, 0.f, 0.f, 0.f}, a1 = a0, a2 = a0;
#pragma unroll
        for (int t6 = 0; t6 < 6; ++t6) {
            int g  = t6 * 4 + quad;          // tap group: c = g/8, ky = g%8
            int c  = g >> 3, ky = g & 7;
            const unsigned* lp = (const unsigned*)(ldsimg + c * CL_CH + (oyl * 4 + ky) * CL_STRIDE + ox * 4 + 2);
            bf16x8 afr;
            unsigned* ap = (unsigned*)&afr;
            ap[0] = lp[0]; ap[1] = lp[1]; ap[2] = lp[2]; ap[3] = lp[3];
            a0 = __builtin_amdgcn_mfma_f32_16x16x32_bf16(afr, bw[t6][0], a0, 0, 0, 0);
            a1 = __builtin_amdgcn_mfma_f32_16x16x32_bf16(afr, bw[t6][1], a1, 0, 0, 0);
            a2 = __builtin_amdgcn_mfma_f32_16x16x32_bf16(afr, bw[t6][2], a2, 0, 0, 0);
        }
        // C/D layout: out position = mt*16 + quad*4 + reg, out ch = lcol
        const int base = h * 192 + mt * 16 + quad * 4;
        ushort4 ou, of, os;
        {
            float u0 = a0[0] + bu, u1 = a0[1] + bu, u2 = a0[2] + bu, u3 = a0[3] + bu;
            ou.x = bf16u(u0 > 0.f ? u0 : 0.f);
            ou.y = bf16u(u1 > 0.f ? u1 : 0.f);
            ou.z = bf16u(u2 > 0.f ? u2 : 0.f);
            ou.w = bf16u(u3 > 0.f ? u3 : 0.f);
            of.x = bf16u(a1[0] + bb); of.y = bf16u(a1[1] + bb);
            of.z = bf16u(a1[2] + bb); of.w = bf16u(a1[3] + bb);
            os.x = bf16u(a2[0]); os.y = bf16u(a2[1]);
            os.z = bf16u(a2[2]); os.w = bf16u(a2[3]);
        }
        *(ushort4*)(Aur + lcol * 384 + base) = ou;
        *(ushort4*)(yfr + lcol * 384 + base) = of;
        *(ushort4*)(ysr + lcol * 384 + base) = os;
    }
}

// ---------------------------------------------------------------------------
// Kernel 3: fused expand + split-K bf16 MFMA GEMM.
// M = 3456 as 54 tiles of 64 rows (48 binary + 6 unary), N = 128 (100 used),
// K = 6144 in 8 chunks. Binary A-tiles built on the fly from yfb/ysb.
// Block 256 thr (4 waves, 2x2), wave tile 32x64. Grid 432.
// ---------------------------------------------------------------------------
__global__ __launch_bounds__(256) void gemm_kernel(
    const unsigned short* __restrict__ yfb, const unsigned short* __restrict__ ysb,
    const unsigned short* __restrict__ Au,
    const unsigned short* __restrict__ Btb, const unsigned short* __restrict__ Btu,
    float* __restrict__ partial)
{
    const int tid = threadIdx.x;
    const int mt = blockIdx.x % 54;
    const int kc = blockIdx.x / 54;      // 0..7

    __shared__ __align__(16) unsigned short lsA[64 * 72];
    __shared__ __align__(16) unsigned short lsB[128 * 72];

    const int lane = tid & 63;
    const int w  = tid >> 6;
    const int wr = w & 1;
    const int wc = w >> 1;
    const int quad = lane >> 4;
    const int lcol = lane & 15;

    f32x4 acc[2][4];
#pragma unroll
    for (int i = 0; i < 2; ++i)
#pragma unroll
        for (int j = 0; j < 4; ++j) acc[i][j] = (f32x4){0.f, 0.f, 0.f, 0.f};

    // A staging: thread covers row ra (0..63), k-quarter qa (16 bf16)
    const int ra = tid >> 2, qa = tid & 3;
    const bool fused = (mt < 48);
    const unsigned short *pf, *ps = nullptr;
    if (fused) {
        int g = mt * 64 + ra;                // global binary pair row
        int si = g >> 10, gs = g & 1023;
        int b = gs >> 6, i = (gs >> 3) & 7, j = gs & 7;
        pf = yfb + (long)(si * 128 + b * 8 + i) * 6144;
        ps = ysb + (long)(si * 128 + b * 8 + j) * 6144;
    } else {
        pf = Au + (long)((mt - 48) * 64 + ra) * 6144;
    }
    const unsigned short* Bt = fused ? Btb : Btu;
    const int rb = tid >> 1, hb = tid & 1;
    const long brow = (long)rb * 6144;
    const int kbase0 = kc * 768;

    for (int it = 0; it < 12; ++it) {
        const int kb = kbase0 + it * 64;
        // global loads first (latency overlap)
        const uint4* gb = (const uint4*)(Bt + brow + kb + hb * 32);
        uint4 b0 = gb[0], b1 = gb[1], b2 = gb[2], b3 = gb[3];
        const uint4* gf = (const uint4*)(pf + kb + qa * 16);
        uint4 f0 = gf[0], f1 = gf[1];
        if (fused) {
            const uint4* gs2 = (const uint4*)(ps + kb + qa * 16);
            uint4 s0 = gs2[0], s1 = gs2[1];
            f0.x = pair_relu(f0.x, s0.x); f0.y = pair_relu(f0.y, s0.y);
            f0.z = pair_relu(f0.z, s0.z); f0.w = pair_relu(f0.w, s0.w);
            f1.x = pair_relu(f1.x, s1.x); f1.y = pair_relu(f1.y, s1.y);
            f1.z = pair_relu(f1.z, s1.z); f1.w = pair_relu(f1.w, s1.w);
        }
        uint4* da = (uint4*)(lsA + ra * 72 + qa * 16);
        uint4* db = (uint4*)(lsB + rb * 72 + hb * 32);
        da[0] = f0; da[1] = f1;
        db[0] = b0; db[1] = b1; db[2] = b2; db[3] = b3;
        __syncthreads();
#pragma unroll
        for (int ks = 0; ks < 2; ++ks) {
            bf16x8 af[2], bfr[4];
#pragma unroll
            for (int t = 0; t < 2; ++t)
                af[t] = *(const bf16x8*)(lsA + (wr * 32 + t * 16 + lcol) * 72 + ks * 32 + quad * 8);
#pragma unroll
            for (int t = 0; t < 4; ++t)
                bfr[t] = *(const bf16x8*)(lsB + (wc * 64 + t * 16 + lcol) * 72 + ks * 32 + quad * 8);
#pragma unroll
            for (int i = 0; i < 2; ++i)
#pragma unroll
                for (int j = 0; j < 4; ++j)
                    acc[i][j] = __builtin_amdgcn_mfma_f32_16x16x32_bf16(af[i], bfr[j], acc[i][j], 0, 0, 0);
        }
        __syncthreads();
    }

    float* out = partial + (long)(kc * 54 + mt) * 8192;
#pragma unroll
    for (int i = 0; i < 2; ++i)
#pragma unroll
        for (int j = 0; j < 4; ++j)
#pragma unroll
            for (int reg = 0; reg < 4; ++reg) {
                int rr = wr * 32 + i * 16 + quad * 4 + reg;
                int cc = wc * 64 + j * 16 + lcol;
                out[rr * 128 + cc] = acc[i][j][reg];
            }
}

// ---------------------------------------------------------------------------
// Kernel 4: split-K reduce + bias + relu + FC2 -> logits (3456 x 2 f32).
// Block = 16 rows x 16 lanes; shuffle-reduce the FC2 dot across 16 lanes.
// ---------------------------------------------------------------------------
__global__ __launch_bounds__(256) void reducefc2_kernel(
    const float* __restrict__ partial,
    const float* __restrict__ b2b, const float* __restrict__ b2u,
    const float* __restrict__ W3b, const float* __restrict__ b3b,
    const float* __restrict__ W3u, const float* __restrict__ b3u,
    float* __restrict__ logits)
{
    const int tid = threadIdx.x;
    const int m = blockIdx.x * 16 + (tid >> 4);   // 216 blocks -> 3456 rows
    const int c = tid & 15;
    const int mt = m >> 6, rr = m & 63;
    const bool un = (m >= 3072);
    const float* b2 = un ? b2u : b2b;
    const float* W3 = un ? W3u : W3b;
    float l0 = 0.f, l1 = 0.f;
    for (int f = c; f < 100; f += 16) {
        float s = b2[f];
#pragma unroll
        for (int kc = 0; kc < 8; ++kc)
            s += partial[((long)(kc * 54 + mt) * 64 + rr) * 128 + f];
        float hv = s > 0.f ? s : 0.f;
        l0 = fmaf(hv, W3[f * 2],     l0);
        l1 = fmaf(hv, W3[f * 2 + 1], l1);
    }
#pragma unroll
    for (int off = 8; off >= 1; off >>= 1) {
        l0 += __shfl_xor(l0, off);
        l1 += __shfl_xor(l1, off);
    }
    if (c == 0) {
        const float* b3 = un ? b3u : b3b;
        logits[m * 2]     = l0 + b3[0];
        logits[m * 2 + 1] = l1 + b3[1];
    }
}

// ---------------------------------------------------------------------------
// Kernel 5: gumbel softmax (2-way -> sigmoid) + compaction/mask -> d_out
// ---------------------------------------------------------------------------
__global__ __launch_bounds__(64) void final_kernel(
    const float* __restrict__ logits,
    const float* __restrict__ gb, const float* __restrict__ gu,
    const int* __restrict__ nobj, const float* __restrict__ temp_p,
    float* __restrict__ out)
{
    int gid = blockIdx.x * 64 + threadIdx.x;
    if (gid >= 3456) return;
    float temp = temp_p[0];
    if (gid < 3072) {
        int si = gid / 1024, rem = gid % 1024;
        int b = rem >> 6, p = rem & 63;
        int n = nobj[b];
        int ns = n > 0 ? n : 1;
        int k = (p / ns) * 8 + (p % ns);
        int valid = p < n * n;
        int kk = k < 63 ? k : 63;
        int src = si * 1024 + b * 64 + kk;
        float l0 = logits[src * 2], l1 = logits[src * 2 + 1];
        const float* g = gb + (long)src * 2;
        float d = ((l0 + g[0]) - (l1 + g[1])) / temp;
        float p0 = 1.f / (1.f + expf(-d));
        float* o = out + (long)si * 2048 + (b * 64 + p) * 2;
        o[0] = valid ? p0 : 0.f;
        o[1] = valid ? 1.f - p0 : 0.f;
    } else {
        int r = gid - 3072;
        int si = r / 128, q = r % 128;
        int b = q >> 3, i = q & 7;
        int src = 3072 + r;
        float l0 = logits[src * 2], l1 = logits[src * 2 + 1];
        const float* g = gu + (long)si * 256 + q * 2;
        float d = ((l0 + g[0]) - (l1 + g[1])) / temp;
        float p0 = 1.f / (1.f + expf(-d));
        int valid = i < nobj[b];
        float* o = out + 6144 + (long)si * 256 + q * 2;
        o[0] = valid ? p0 : 0.f;
        o[1] = valid ? 1.f - p0 : 0.f;
    }
}

// ---------------------------------------------------------------------------
// Workspace layout (bytes)
// ---------------------------------------------------------------------------
static const size_t YFB_OFF  = 0;                          // 384*6144 bf16 = 4,718,592
static const size_t YSB_OFF  = 4718592;                    // 4,718,592
static const size_t AU_OFF   = 9437184;                    // 4,718,592
static const size_t BTB_OFF  = 14155776;                   // 1,572,864
static const size_t BTU_OFF  = 15728640;                   // 1,572,864
static const size_t PART_OFF = 17301504;                   // 8*54*64*128 f32 = 14,155,776
static const size_t LOG_OFF  = 31457280;                   // 3456*2 f32 = 27,648
static const size_t BWF_OFF  = 31484928;                   // 18*64*8 bf16 = 18,432
// total = 31,503,360 bytes

extern "C" void kernel_launch(void* const* d_in, const int* in_sizes, int n_in,
                              void* d_out, int out_size, void* d_ws, size_t ws_size,
                              hipStream_t stream) {
    const float* state   = (const float*)d_in[0];
    const float* state_n = (const float*)d_in[1];
    const float* state_t = (const float*)d_in[2];
    const int*   n_obj   = (const int*)  d_in[3];
    const float* temp    = (const float*)d_in[4];
    const float* g_un    = (const float*)d_in[5];
    const float* g_bin   = (const float*)d_in[6];
    const float* Wc_u    = (const float*)d_in[7];
    const float* bc_u    = (const float*)d_in[8];
    const float* W2_u    = (const float*)d_in[9];
    const float* b2_u    = (const float*)d_in[10];
    const float* W3_u    = (const float*)d_in[11];
    const float* b3_u    = (const float*)d_in[12];
    const float* Wc_b    = (const float*)d_in[13];
    const float* bc_b    = (const float*)d_in[14];
    const float* W2_b    = (const float*)d_in[15];
    const float* b2_b    = (const float*)d_in[16];
    const float* W3_b    = (const float*)d_in[17];
    const float* b3_b    = (const float*)d_in[18];

    char* ws = (char*)d_ws;
    unsigned short* yfb  = (unsigned short*)(ws + YFB_OFF);
    unsigned short* ysb  = (unsigned short*)(ws + YSB_OFF);
    unsigned short* Au   = (unsigned short*)(ws + AU_OFF);
    unsigned short* Btb  = (unsigned short*)(ws + BTB_OFF);
    unsigned short* Btu  = (unsigned short*)(ws + BTU_OFF);
    float*          prt  = (float*)(ws + PART_OFF);
    float*          lg   = (float*)(ws + LOG_OFF);
    unsigned short* BwF  = (unsigned short*)(ws + BWF_OFF);
    float*          out  = (float*)d_out;

    hipLaunchKernelGGL(convertB_kernel, dim3(97), dim3(256), 0, stream,
                       W2_b, W2_u, Wc_u, Wc_b, Btb, Btu, BwF);
    hipLaunchKernelGGL(convmfma_kernel, dim3(768), dim3(256), 0, stream,
                       state, state_n, state_t, BwF, bc_u, bc_b, Au, yfb, ysb);
    hipLaunchKernelGGL(gemm_kernel, dim3(432), dim3(256), 0, stream,
                       yfb, ysb, Au, Btb, Btu, prt);
    hipLaunchKernelGGL(reducefc2_kernel, dim3(216), dim3(256), 0, stream,
                       prt, b2_b, b2_u, W3_b, b3_b, W3_u, b3_u, lg);
    hipLaunchKernelGGL(final_kernel, dim3(54), dim3(64), 0, stream,
                       lg, g_bin, g_un, n_obj, temp, out);
}